// Round 7
// baseline (56.196 us; speedup 1.0000x reference)
//
#include <hip/hip_runtime.h>
#include <hip/hip_bf16.h>

// LS2T iterated sums (ORDER=3): B=64, T=4096, D=128, F=64, C=6.
// m_c(t,f) = seq[b,t,:]·kernel[c,:,f] + bias[c,f]
// Y1 = sum m0; Y2 = sum m2*cumx(m1); Y3 = sum m5*cumx(m4*cumx(m3))
//
// Round 7: WAVE-AUTONOMOUS. Each wave owns (b, 128-t span, 16 f, all 6 c):
// loads its own chunks coalesced from global, packs f32->bf16 (v_perm trunc),
// stages through a PRIVATE 4KB-double-buffered LDS transpose (XOR-swizzled),
// MFMAs with B-frags held in registers (6c x 4ks = 96 VGPR), chains the scan
// lane-locally. NO __syncthreads anywhere: same-wave LDS ordering is free.
// 4 waves/block share the span so global re-reads hit L1/L2.

#define B_ 64
#define T_ 4096
#define D_ 128
#define F_ 64
#define NC 6
#define SPAN 128
#define NSPAN (T_ / SPAN)     // 32
#define CHT 16                // t per chunk
#define NITER (SPAN / CHT)    // 8
#define TPB 256

typedef __attribute__((ext_vector_type(8))) short short8v;
typedef __attribute__((ext_vector_type(4))) float f32x4;

__device__ __forceinline__ unsigned short bfb(float x) {
    __hip_bfloat16 h = __float2bfloat16(x);   // RNE (used for B only)
    unsigned short u;
    __builtin_memcpy(&u, &h, 2);
    return u;
}

__global__ __launch_bounds__(TPB, 2)
void ls2t_kernel(const float* __restrict__ seq,
                 const float* __restrict__ kern,
                 const float* __restrict__ bias,
                 float* __restrict__ ws)
{
    __shared__ unsigned short slds[4][2][CHT * D_];   // per-wave 2 x 4 KB

    const int tid  = threadIdx.x;
    const int span = blockIdx.x;
    const int b    = blockIdx.y;
    const int lane = tid & 63;
    const int wv   = tid >> 6;     // wave id -> f-range
    const int fr   = lane & 15;
    const int lg   = lane >> 4;
    const int f    = wv * 16 + fr;

    // ---- B fragments in registers (B: col=lane&15=f, k=(lane>>4)*8+j) ----
    short8v bfrag[NC][4];
    float bc[NC];
    #pragma unroll
    for (int c = 0; c < NC; ++c) {
        bc[c] = bias[c * F_ + f];
        #pragma unroll
        for (int ks = 0; ks < 4; ++ks) {
            const float* kp = kern + ((size_t)c * D_ + ks * 32 + lg * 8) * F_ + f;
            short8v bf;
            #pragma unroll
            for (int j = 0; j < 8; ++j) bf[j] = (short)bfb(kp[(size_t)j * F_]);
            bfrag[c][ks] = bf;
        }
    }

    const float* sbase = seq + ((size_t)b * T_ + (size_t)span * SPAN) * D_;

    // load geometry: load k covers rows {2k, 2k+1} of the 16-row chunk;
    // lane: srow0 = lane>>5 (which of the 2 rows), sd4 = float4 index 0..31.
    // chunk row r holds t_local = (r>>2)*32 + i*4 + (r&3): lane-group lg owns
    // contiguous t-stripe [lg*32, +32) across the 8 chunks.
    const int srow0 = lane >> 5;
    const int sd4   = lane & 31;

    unsigned short* const L0 = &slds[wv][0][0];
    unsigned short* const L1 = &slds[wv][1][0];

    float4 fA[8];

    auto issue = [&](int i) {
        #pragma unroll
        for (int k = 0; k < 8; ++k) {
            const int row = 2 * k + srow0;
            const int tl  = (row >> 2) * 32 + (row & 3) + i * 4;
            fA[k] = *reinterpret_cast<const float4*>(
                sbase + (size_t)tl * D_ + sd4 * 4);
        }
    };

    // pack f32->bf16 (truncation) and write 8B to the swizzled transpose tile
    auto packw = [&](unsigned short* L) {
        #pragma unroll
        for (int k = 0; k < 8; ++k) {
            const int row = 2 * k + srow0;
            unsigned u0 = __float_as_uint(fA[k].x);
            unsigned u1 = __float_as_uint(fA[k].y);
            unsigned u2 = __float_as_uint(fA[k].z);
            unsigned u3 = __float_as_uint(fA[k].w);
            unsigned p0 = __builtin_amdgcn_perm(u1, u0, 0x07060302u); // [bf(x),bf(y)]
            unsigned p1 = __builtin_amdgcn_perm(u3, u2, 0x07060302u); // [bf(z),bf(w)]
            // shorts offset: row*128 + swizzled 16B-unit*8 + 4B-half*4
            const int off = row * 128 + (((sd4 >> 1) ^ (row & 15)) << 3)
                          + ((sd4 & 1) << 2);
            uint2 pv; pv.x = p0; pv.y = p1;
            *reinterpret_cast<uint2*>(&L[off]) = pv;
        }
    };

    // scan state (all 6 chains, this lane's 16-f column f)
    float a0 = 0.f, s1 = 0.f, s2 = 0.f, q2 = 0.f;
    float su = 0.f, sv = 0.f, sw = 0.f, qvu = 0.f, qwv = 0.f, qwvu = 0.f;

    auto compute = [&](const unsigned short* L) {
        f32x4 acc[NC];
        #pragma unroll
        for (int c = 0; c < NC; ++c)
            acc[c] = (f32x4){bc[c], bc[c], bc[c], bc[c]};

        #pragma unroll
        for (int ks = 0; ks < 4; ++ks) {
            const int unit = (ks * 4 + lg) ^ (fr & 15);
            short8v a = *reinterpret_cast<const short8v*>(&L[fr * 128 + unit * 8]);
            #pragma unroll
            for (int c = 0; c < NC; ++c)
                acc[c] = __builtin_amdgcn_mfma_f32_16x16x32_bf16(
                    a, bfrag[c][ks], acc[c], 0, 0, 0);
        }

        // lane owns t = span*128 + lg*32 + i*4 + r -> chain in-lane
        #pragma unroll
        for (int r = 0; r < 4; ++r) {
            float m0 = acc[0][r], m1 = acc[1][r], m2 = acc[2][r];
            float m3 = acc[3][r], m4 = acc[4][r], m5 = acc[5][r];
            a0  += m0;
            q2   = fmaf(m2, s1, q2);      // s1 = exclusive cumsum(m1)
            s2  += m2;
            s1  += m1;
            qwvu = fmaf(m5, qvu, qwvu);
            qwv  = fmaf(m5, sv, qwv);
            sw  += m5;
            qvu  = fmaf(m4, su, qvu);
            sv  += m4;
            su  += m3;
        }
    };

    // ---- free-running pipeline: depth-1 chunk prefetch, private dbuf ----
    issue(0);
    packw(L0);        // waits its loads, packs, writes buf0
    issue(1);

    #pragma unroll 1
    for (int i = 0; i < NITER; i += 2) {
        compute(L0);                          // chunk i
        packw(L1);                            // chunk i+1 -> buf1
        if (i + 2 < NITER) issue(i + 2);
        compute(L1);                          // chunk i+1
        if (i + 2 < NITER) packw(L0);         // chunk i+2 -> buf0
        if (i + 3 < NITER) issue(i + 3);
    }

    // ---- merge the 4 lane-group stripes (time order: lg ascending) ----
    #pragma unroll
    for (int m = 16; m <= 32; m <<= 1) {
        float oa0 = __shfl_xor(a0, m),   os1 = __shfl_xor(s1, m);
        float os2 = __shfl_xor(s2, m),   oq2 = __shfl_xor(q2, m);
        float osu = __shfl_xor(su, m),   osv = __shfl_xor(sv, m);
        float osw = __shfl_xor(sw, m),   oqvu = __shfl_xor(qvu, m);
        float oqwv = __shfl_xor(qwv, m), oqwvu = __shfl_xor(qwvu, m);
        const bool up = (lane & m) != 0;   // this lane holds the LATER segment
        float Aa0 = up ? oa0 : a0,   Ba0 = up ? a0 : oa0;
        float As1 = up ? os1 : s1,   Bs1 = up ? s1 : os1;
        float As2 = up ? os2 : s2,   Bs2 = up ? s2 : os2;
        float Aq2 = up ? oq2 : q2,   Bq2 = up ? q2 : oq2;
        float Asu = up ? osu : su,   Bsu = up ? su : osu;
        float Asv = up ? osv : sv,   Bsv = up ? sv : osv;
        float Asw = up ? osw : sw,   Bsw = up ? sw : osw;
        float Aqvu = up ? oqvu : qvu,   Bqvu = up ? qvu : oqvu;
        float Aqwv = up ? oqwv : qwv,   Bqwv = up ? qwv : oqwv;
        float Aqwvu = up ? oqwvu : qwvu, Bqwvu = up ? qwvu : oqwvu;
        a0   = Aa0 + Ba0;
        q2   = Aq2 + Bq2 + As1 * Bs2;
        s1   = As1 + Bs1;
        s2   = As2 + Bs2;
        qwvu = Aqwvu + Bqwvu + Aqvu * Bsw + Asu * Bqwv;
        qwv  = Aqwv + Bqwv + Asv * Bsw;
        qvu  = Aqvu + Bqvu + Asu * Bsv;
        su   = Asu + Bsu;
        sv   = Asv + Bsv;
        sw   = Asw + Bsw;
    }

    if (lg == 0) {
        float* wp = ws + (((size_t)b * NSPAN + span) * F_ + f) * 10;
        wp[0] = a0;  wp[1] = s1;  wp[2] = s2;  wp[3] = q2;
        wp[4] = su;  wp[5] = sv;  wp[6] = sw;
        wp[7] = qvu; wp[8] = qwv; wp[9] = qwvu;
    }
}

struct St { float a0, s1, s2, q2, su, sv, sw, qvu, qwv, qwvu; };

__device__ __forceinline__ St mergeSt(const St& A, const St& B) {
    St r;
    r.a0   = A.a0 + B.a0;
    r.q2   = A.q2 + B.q2 + A.s1 * B.s2;
    r.s1   = A.s1 + B.s1;
    r.s2   = A.s2 + B.s2;
    r.qwvu = A.qwvu + B.qwvu + A.qvu * B.sw + A.su * B.qwv;
    r.qwv  = A.qwv + B.qwv + A.sv * B.sw;
    r.qvu  = A.qvu + B.qvu + A.su * B.sv;
    r.su   = A.su + B.su;
    r.sv   = A.sv + B.sv;
    r.sw   = A.sw + B.sw;
    return r;
}

__global__ __launch_bounds__(64)
void ls2t_fold_kernel(const float* __restrict__ ws, float* __restrict__ out)
{
    const int b = blockIdx.x;
    const int f = threadIdx.x;
    St A = {0, 0, 0, 0, 0, 0, 0, 0, 0, 0};
    #pragma unroll
    for (int g = 0; g < NSPAN; ++g) {
        const float* rp = ws + (((size_t)b * NSPAN + g) * F_ + f) * 10;
        St r = {rp[0], rp[1], rp[2], rp[3], rp[4],
                rp[5], rp[6], rp[7], rp[8], rp[9]};
        A = mergeSt(A, r);
    }
    float* op = out + ((size_t)b * F_ + f) * 3;
    op[0] = A.a0;
    op[1] = A.q2;
    op[2] = A.qwvu;
}

extern "C" void kernel_launch(void* const* d_in, const int* in_sizes, int n_in,
                              void* d_out, int out_size, void* d_ws, size_t ws_size,
                              hipStream_t stream) {
    const float* seq  = (const float*)d_in[0];
    const float* kern = (const float*)d_in[1];
    const float* bias = (const float*)d_in[2];
    float* out = (float*)d_out;
    float* ws  = (float*)d_ws;   // B_*NSPAN*F_*10*4 = 5.24 MB

    dim3 g1(NSPAN, B_);          // 2048 blocks x 256 thr
    ls2t_kernel<<<g1, TPB, 0, stream>>>(seq, kern, bias, ws);
    ls2t_fold_kernel<<<B_, F_, 0, stream>>>(ws, out);
}